// Round 14
// baseline (885.417 us; speedup 1.0000x reference)
//
#include <hip/hip_runtime.h>

#define DEV __device__ __forceinline__

DEV float relu(float v) { return v > 0.f ? v : 0.f; }

// ---- small-region layout (float offsets) ----
#define G1_OFF 0
#define GIN_OFF 16
#define WEE 48
#define BEE 64
#define WC  80      // We_core [98][16]
#define BC  1648
#define WD  1664    // We_dec [16][16]
#define BD  1920
#define WO  1936    // We_out [16][2]
#define BO  1968
#define WXE 1972
#define BXE 1988
#define WXC 2004    // Wx_core [50][16]
#define BXC 2804
#define WXD 2820
#define BXD 3076
#define WXO 3092
#define BXO 3124
#define WGE 3126
#define BGE 3127
#define WGC 3128
#define BGC 3162
#define WGD 3163
#define BGD 3164
#define WGO 3165
#define BGO 3166
#define SMALL_N 3200

struct P {
    const float *x, *e, *g;
    const int *src, *dst, *nidx, *eidx;
    float *ec, *xin, *agg, *small, *eagg_rep, *nagg_rep;  // ec CSR-ordered
    int *cnt, *rowptr, *cursor, *origidx;
    float *eperm;        // e values in CSR order
    int *spk;            // src | (eidx<<24) in CSR order
    int *dstperm;        // dst in CSR order (sorted)
    float *out;
    int N, E, B;
};

struct WIn {
    const float *we_enc, *be_enc, *wx_enc, *bx_enc, *wg_enc, *bg_enc;
    const float *wc, *bc, *wxc, *bxc, *wgc, *bgc;
    const float *wd, *bd, *wxd, *bxd, *wgd, *bgd;
    const float *wo, *bo, *wxo, *bxo, *wgo, *bgo;
};

__global__ __launch_bounds__(256) void k_init_small(P p, WIn w) {
    int t = threadIdx.x;
    float* S = p.small;
#define CP(ptr, off, len) for (int i = t; i < (len); i += 256) S[(off) + i] = ptr[i];
    CP(w.we_enc, WEE, 16) CP(w.be_enc, BEE, 16)
    CP(w.wc, WC, 1568)    CP(w.bc, BC, 16)
    CP(w.wd, WD, 256)     CP(w.bd, BD, 16)
    CP(w.wo, WO, 32)      CP(w.bo, BO, 2)
    CP(w.wx_enc, WXE, 16) CP(w.bx_enc, BXE, 16)
    CP(w.wxc, WXC, 800)   CP(w.bxc, BXC, 16)
    CP(w.wxd, WXD, 256)   CP(w.bxd, BXD, 16)
    CP(w.wxo, WXO, 32)    CP(w.bxo, BXO, 2)
    CP(w.wgc, WGC, 34)
#undef CP
    if (t == 0) {
        S[WGE] = w.wg_enc[0]; S[BGE] = w.bg_enc[0];
        S[BGC] = w.bgc[0];
        S[WGD] = w.wgd[0];    S[BGD] = w.bgd[0];
        S[WGO] = w.wgo[0];    S[BGO] = w.bgo[0];
    }
    if (t < p.B) {
        float gv = p.g[t];
        float g1 = relu(gv * w.wg_enc[0] + w.bg_enc[0]);
        S[G1_OFF + t] = g1;
        S[GIN_OFF + 2 * t] = g1;
        S[GIN_OFF + 2 * t + 1] = g1;   // gc starts as g1
    }
    for (int r = t; r < 16 * 256; r += 256) p.nagg_rep[r] = 0.f;
    for (int r = t; r < 64 * 256; r += 256) p.eagg_rep[r] = 0.f;
}

__global__ __launch_bounds__(256) void k_init_nodes(P p, WIn w) {
    size_t n = (size_t)blockIdx.x * 256 + threadIdx.x;
    if (n >= (size_t)p.N) return;
    p.cnt[n] = 0;
    float xv = p.x[n];
    float* row = p.xin + n * 32;
#pragma unroll
    for (int h = 0; h < 16; h++) {
        float v = relu(xv * w.wx_enc[h] + w.bx_enc[h]);
        row[h] = v;
        row[16 + h] = v;   // xc starts as x1
    }
    float4 z = make_float4(0.f, 0.f, 0.f, 0.f);
    float4* a = (float4*)(p.agg + n * 16);
#pragma unroll
    for (int c = 0; c < 4; c++) a[c] = z;   // boundary-run atomics need zeroed base
}

__global__ __launch_bounds__(256) void k_hist(P p) {
    size_t i = (size_t)blockIdx.x * 256 + threadIdx.x;
    if (i >= (size_t)p.E) return;
    atomicAdd(&p.cnt[p.dst[i]], 1);
}

// single-block exclusive scan of cnt[0..N) -> rowptr[0..N] and cursor copy
#define SCAN_T 1024
#define SCAN_V 4
__global__ __launch_bounds__(SCAN_T) void k_scan(P p) {
    __shared__ int wsum[16];
    __shared__ int carry_s;
    int t = threadIdx.x;
    int lane = t & 63, wid = t >> 6;
    if (t == 0) carry_s = 0;
    __syncthreads();
    int chunk = SCAN_T * SCAN_V;
    int nchunk = (p.N + chunk - 1) / chunk;
    for (int c = 0; c < nchunk; c++) {
        int base = c * chunk + t * SCAN_V;
        int v[SCAN_V];
        int s = 0;
#pragma unroll
        for (int k = 0; k < SCAN_V; k++) {
            int idx = base + k;
            v[k] = (idx < p.N) ? p.cnt[idx] : 0;
            s += v[k];
        }
        int incl = s;
#pragma unroll
        for (int off = 1; off < 64; off <<= 1) {
            int u = __shfl_up(incl, off);
            if (lane >= off) incl += u;
        }
        if (lane == 63) wsum[wid] = incl;
        __syncthreads();
        if (wid == 0) {
            int ws = (lane < 16) ? wsum[lane] : 0;
            int wincl = ws;
#pragma unroll
            for (int off = 1; off < 16; off <<= 1) {
                int u = __shfl_up(wincl, off);
                if (lane >= off) wincl += u;
            }
            if (lane < 16) wsum[lane] = wincl - ws;
        }
        __syncthreads();
        int carry = carry_s;
        int excl = carry + wsum[wid] + incl - s;
        int run = excl;
#pragma unroll
        for (int k = 0; k < SCAN_V; k++) {
            int idx = base + k;
            if (idx < p.N) { p.rowptr[idx] = run; p.cursor[idx] = run; }
            run += v[k];
        }
        __syncthreads();
        if (t == SCAN_T - 1) carry_s = excl + s;
        __syncthreads();
    }
    if (t == 0) p.rowptr[p.N] = carry_s;
}

// merged scatter+permute: place each edge directly into its CSR slot
__global__ __launch_bounds__(256) void k_build(P p) {
    size_t i = (size_t)blockIdx.x * 256 + threadIdx.x;
    if (i >= (size_t)p.E) return;
    int d = p.dst[i];
    int slot = atomicAdd(&p.cursor[d], 1);
    p.eperm[slot] = p.e[i];
    p.spk[slot] = p.src[i] | (p.eidx[i] << 24);
    p.dstperm[slot] = d;
    p.origidx[slot] = (int)i;
}

template <int STEP0, int SAVE_EC>
__global__ __launch_bounds__(256) void k_edge(P p, int s) {
    __shared__ float eagg_lds[4][16 * 17];   // per-wave replicas: ~4-way atomic collisions
    __shared__ float sagg[16][257];          // transposed; 257%32==1 -> rotated banks, conflict-free
    __shared__ int sd[256];
    const int t = threadIdx.x;
    const int wv = t >> 6;
    for (int r = t; r < 4 * 16 * 17; r += 256) eagg_lds[0][r] = 0.f;
    __syncthreads();
    const size_t j = (size_t)blockIdx.x * 256 + t;
    const float* __restrict__ S = p.small;
    float enew[16];
#pragma unroll
    for (int h = 0; h < 16; h++) enew[h] = 0.f;
    int di = -1;
    const bool valid = j < (size_t)p.E;
    if (valid) {
        float acc[16];
#pragma unroll
        for (int h = 0; h < 16; h++) acc[h] = S[BC + h];
        float ev = p.eperm[j];
        unsigned sp = (unsigned)p.spk[j];
        int si = (int)(sp & 0xFFFFFFu);
        int b = (int)(sp >> 24);
        di = p.dstperm[j];
        float e1v[16];
#pragma unroll
        for (int h = 0; h < 16; h++) e1v[h] = relu(ev * S[WEE + h] + S[BEE + h]);
#pragma unroll
        for (int jj = 0; jj < 16; jj++)
#pragma unroll
            for (int h = 0; h < 16; h++) acc[h] += e1v[jj] * S[WC + jj * 16 + h];
        if (STEP0) {
#pragma unroll
            for (int jj = 0; jj < 16; jj++)
#pragma unroll
                for (int h = 0; h < 16; h++) acc[h] += e1v[jj] * S[WC + (16 + jj) * 16 + h];
        } else {
            const float4* ecv = (const float4*)(p.ec + j * 16);
#pragma unroll
            for (int c = 0; c < 4; c++) {
                float4 v = ecv[c];
                float vv[4] = {v.x, v.y, v.z, v.w};
#pragma unroll
                for (int k = 0; k < 4; k++)
#pragma unroll
                    for (int h = 0; h < 16; h++) acc[h] += vv[k] * S[WC + (16 + c * 4 + k) * 16 + h];
            }
        }
        // x_in[src] random gather; x_in[dst] wave-local (dst sorted)
        const float4* xs = (const float4*)(p.xin + (size_t)si * 32);
#pragma unroll
        for (int c = 0; c < 8; c++) {
            float4 v = xs[c];
            float vv[4] = {v.x, v.y, v.z, v.w};
#pragma unroll
            for (int k = 0; k < 4; k++)
#pragma unroll
                for (int h = 0; h < 16; h++) acc[h] += vv[k] * S[WC + (32 + c * 4 + k) * 16 + h];
        }
        const float4* xd = (const float4*)(p.xin + (size_t)di * 32);
#pragma unroll
        for (int c = 0; c < 8; c++) {
            float4 v = xd[c];
            float vv[4] = {v.x, v.y, v.z, v.w};
#pragma unroll
            for (int k = 0; k < 4; k++)
#pragma unroll
                for (int h = 0; h < 16; h++) acc[h] += vv[k] * S[WC + (64 + c * 4 + k) * 16 + h];
        }
        float g0 = S[GIN_OFF + 2 * b], gcv = S[GIN_OFF + 2 * b + 1];
#pragma unroll
        for (int h = 0; h < 16; h++) acc[h] += g0 * S[WC + 96 * 16 + h] + gcv * S[WC + 97 * 16 + h];
#pragma unroll
        for (int h = 0; h < 16; h++) enew[h] = relu(acc[h]);
        if (SAVE_EC) {   // next step's k_edge input; dead on the last step
            float4* eco = (float4*)(p.ec + j * 16);
#pragma unroll
            for (int c = 0; c < 4; c++)
                eco[c] = make_float4(enew[c * 4], enew[c * 4 + 1], enew[c * 4 + 2], enew[c * 4 + 3]);
        }
        // per-graph edge aggregate (per-wave replica cuts same-address collisions)
#pragma unroll
        for (int h = 0; h < 16; h++) atomicAdd(&eagg_lds[wv][b * 17 + h], enew[h]);
        // fused decoder + output (scattered 8B store at original edge index)
        int i = p.origidx[j];
        float d[16];
#pragma unroll
        for (int h2 = 0; h2 < 16; h2++) d[h2] = S[BD + h2];
#pragma unroll
        for (int h = 0; h < 16; h++)
#pragma unroll
            for (int h2 = 0; h2 < 16; h2++) d[h2] += enew[h] * S[WD + h * 16 + h2];
        float o0 = S[BO], o1 = S[BO + 1];
#pragma unroll
        for (int h2 = 0; h2 < 16; h2++) {
            float dv = relu(d[h2]);
            o0 += dv * S[WO + h2 * 2];
            o1 += dv * S[WO + h2 * 2 + 1];
        }
        ((float2*)p.out)[(size_t)s * p.E + i] = make_float2(o0, o1);
    }
    // stage enew rows (transposed) + dst for segmented aggregation
    sd[t] = di;
#pragma unroll
    for (int h = 0; h < 16; h++) sagg[h][t] = enew[h];
    __syncthreads();
    // segmented sum over dst runs (dst sorted): head threads walk their run
    if (valid && (t == 0 || sd[t - 1] != di)) {
        float sum[16];
#pragma unroll
        for (int h = 0; h < 16; h++) sum[h] = sagg[h][t];
        int k = t + 1;
        while (k < 256 && sd[k] == di) {
#pragma unroll
            for (int h = 0; h < 16; h++) sum[h] += sagg[h][k];
            k++;
        }
        size_t jend = j + (size_t)(k - t);
        int rs = p.rowptr[di], re = p.rowptr[di + 1];
        float* arow = p.agg + (size_t)di * 16;
        if (j == (size_t)rs && jend == (size_t)re) {
            // complete node in this block: plain store
#pragma unroll
            for (int h = 0; h < 16; h++) arow[h] = sum[h];
        } else {
            // run split across blocks: atomic onto zeroed base
#pragma unroll
            for (int h = 0; h < 16; h++) atomicAdd(arow + h, sum[h]);
        }
    }
    // flush block-local edge_agg (sum the 4 wave replicas) to replicated global accumulators
    {
        int idx = (t >> 4) * 17 + (t & 15);
        float v = eagg_lds[0][idx] + eagg_lds[1][idx] + eagg_lds[2][idx] + eagg_lds[3][idx];
        if (v != 0.f)
            atomicAdd(p.eagg_rep + (size_t)(blockIdx.x & 63) * 256 + t, v);
    }
}

__global__ __launch_bounds__(256) void k_node(P p, int s) {
    const size_t n = (size_t)blockIdx.x * 256 + threadIdx.x;
    const bool valid = n < (size_t)p.N;
    const float* __restrict__ S = p.small;
    float xnew[16];
    int b = 0;
    if (valid) {
        float acc[16];
#pragma unroll
        for (int h = 0; h < 16; h++) acc[h] = S[BXC + h];
        float xv = p.x[n];
        float x1v[16];
#pragma unroll
        for (int h = 0; h < 16; h++) x1v[h] = relu(xv * S[WXE + h] + S[BXE + h]);
#pragma unroll
        for (int jj = 0; jj < 16; jj++)
#pragma unroll
            for (int h = 0; h < 16; h++) acc[h] += x1v[jj] * S[WXC + jj * 16 + h];
        const float4* xcv = (const float4*)(p.xin + n * 32 + 16);
#pragma unroll
        for (int c = 0; c < 4; c++) {
            float4 v = xcv[c];
            float vv[4] = {v.x, v.y, v.z, v.w};
#pragma unroll
            for (int k = 0; k < 4; k++)
#pragma unroll
                for (int h = 0; h < 16; h++) acc[h] += vv[k] * S[WXC + (16 + c * 4 + k) * 16 + h];
        }
        // agg_e precomputed by k_edge (rows 32-47); zero for next step after use
        int cnt = p.rowptr[n + 1] - p.rowptr[n];
        float inv = (cnt > 0) ? 1.f / (float)cnt : 1.f;
        float4* arow = (float4*)(p.agg + n * 16);
#pragma unroll
        for (int c = 0; c < 4; c++) {
            float4 v = arow[c];
            float vv[4] = {v.x, v.y, v.z, v.w};
#pragma unroll
            for (int k = 0; k < 4; k++) {
                float av = vv[k] * inv;
#pragma unroll
                for (int h = 0; h < 16; h++) acc[h] += av * S[WXC + (32 + c * 4 + k) * 16 + h];
            }
            arow[c] = make_float4(0.f, 0.f, 0.f, 0.f);
        }
        b = p.nidx[n];
        float g0 = S[GIN_OFF + 2 * b], gcv = S[GIN_OFF + 2 * b + 1];
#pragma unroll
        for (int h = 0; h < 16; h++) acc[h] += g0 * S[WXC + 48 * 16 + h] + gcv * S[WXC + 49 * 16 + h];
#pragma unroll
        for (int h = 0; h < 16; h++) xnew[h] = relu(acc[h]);
        float4* xo = (float4*)(p.xin + n * 32 + 16);
#pragma unroll
        for (int c = 0; c < 4; c++)
            xo[c] = make_float4(xnew[c * 4], xnew[c * 4 + 1], xnew[c * 4 + 2], xnew[c * 4 + 3]);
        float d[16];
#pragma unroll
        for (int h2 = 0; h2 < 16; h2++) d[h2] = S[BXD + h2];
#pragma unroll
        for (int h = 0; h < 16; h++)
#pragma unroll
            for (int h2 = 0; h2 < 16; h2++) d[h2] += xnew[h] * S[WXD + h * 16 + h2];
        float o0 = S[BXO], o1 = S[BXO + 1];
#pragma unroll
        for (int h2 = 0; h2 < 16; h2++) {
            float dv = relu(d[h2]);
            o0 += dv * S[WXO + h2 * 2];
            o1 += dv * S[WXO + h2 * 2 + 1];
        }
        ((float2*)p.out)[(size_t)2 * p.E + (size_t)s * p.N + n] = make_float2(o0, o1);
    } else {
#pragma unroll
        for (int h = 0; h < 16; h++) xnew[h] = 0.f;
    }
    // node_agg: per-wave reduce (node_idx sorted -> wave-uniform almost always)
    int b0 = __shfl(b, 0);
    bool uni = __all(!valid || b == b0);
    float* rep = p.nagg_rep + (size_t)(blockIdx.x & 15) * 256;
    if (uni) {
#pragma unroll
        for (int h = 0; h < 16; h++) {
            float v = xnew[h];
            v += __shfl_down(v, 32); v += __shfl_down(v, 16); v += __shfl_down(v, 8);
            v += __shfl_down(v, 4);  v += __shfl_down(v, 2);  v += __shfl_down(v, 1);
            if ((threadIdx.x & 63) == 0) atomicAdd(rep + b0 * 16 + h, v);
        }
    } else if (valid) {
#pragma unroll
        for (int h = 0; h < 16; h++) atomicAdd(rep + b * 16 + h, xnew[h]);
    }
}

__global__ __launch_bounds__(256) void k_global(P p, int s) {
    __shared__ float na[256], ea[256];
    int t = threadIdx.x;
    float sn = 0.f, se = 0.f;
    for (int r = 0; r < 16; r++) sn += p.nagg_rep[r * 256 + t];
    for (int r = 0; r < 64; r++) se += p.eagg_rep[r * 256 + t];
    na[t] = sn;
    ea[t] = se;
    __syncthreads();
    if (t < p.B) {
        const float* S = p.small;
        float g0 = S[GIN_OFF + 2 * t], gcv = S[GIN_OFF + 2 * t + 1];
        float acc = S[BGC] + g0 * S[WGC + 0] + gcv * S[WGC + 1];
#pragma unroll
        for (int h = 0; h < 16; h++) acc += na[t * 16 + h] * S[WGC + 2 + h];
#pragma unroll
        for (int h = 0; h < 16; h++) acc += ea[t * 16 + h] * S[WGC + 18 + h];
        float gn = relu(acc);
        p.small[GIN_OFF + 2 * t + 1] = gn;
        float gd = relu(gn * S[WGD] + S[BGD]);
        float og = gd * S[WGO] + S[BGO];
        p.out[(size_t)4 * p.E + (size_t)4 * p.N + (size_t)s * p.B + t] = og;
    }
    __syncthreads();
    for (int r = t; r < 16 * 256; r += 256) p.nagg_rep[r] = 0.f;
    for (int r = t; r < 64 * 256; r += 256) p.eagg_rep[r] = 0.f;
}

extern "C" void kernel_launch(void* const* d_in, const int* in_sizes, int n_in,
                              void* d_out, int out_size, void* d_ws, size_t ws_size,
                              hipStream_t stream) {
    int N = in_sizes[0], E = in_sizes[1], B = in_sizes[2];
    P p;
    p.x = (const float*)d_in[0];
    p.e = (const float*)d_in[1];
    p.g = (const float*)d_in[2];
    const int* edges = (const int*)d_in[27];
    p.src = edges;
    p.dst = edges + E;
    p.nidx = (const int*)d_in[28];
    p.eidx = (const int*)d_in[29];

    float* ws = (float*)d_ws;
    size_t off = 0;
    p.ec = ws + off;        off += (size_t)E * 16;
    p.xin = ws + off;       off += (size_t)N * 32;
    p.agg = ws + off;       off += (size_t)N * 16;
    p.eagg_rep = ws + off;  off += 64 * 256;
    p.nagg_rep = ws + off;  off += 16 * 256;
    p.small = ws + off;     off += SMALL_N;
    p.cnt = (int*)(ws + off);     off += N;
    p.rowptr = (int*)(ws + off);  off += (size_t)N + 1;
    p.cursor = (int*)(ws + off);  off += N;
    p.origidx = (int*)(ws + off); off += E;
    p.eperm = ws + off;           off += E;
    p.spk = (int*)(ws + off);     off += E;
    p.dstperm = (int*)(ws + off); off += E;
    p.out = (float*)d_out;
    p.N = N; p.E = E; p.B = B;

    WIn w;
    w.we_enc = (const float*)d_in[3];  w.be_enc = (const float*)d_in[4];
    w.wx_enc = (const float*)d_in[5];  w.bx_enc = (const float*)d_in[6];
    w.wg_enc = (const float*)d_in[7];  w.bg_enc = (const float*)d_in[8];
    w.wc = (const float*)d_in[9];      w.bc = (const float*)d_in[10];
    w.wxc = (const float*)d_in[11];    w.bxc = (const float*)d_in[12];
    w.wgc = (const float*)d_in[13];    w.bgc = (const float*)d_in[14];
    w.wd = (const float*)d_in[15];     w.bd = (const float*)d_in[16];
    w.wxd = (const float*)d_in[17];    w.bxd = (const float*)d_in[18];
    w.wgd = (const float*)d_in[19];    w.bgd = (const float*)d_in[20];
    w.wo = (const float*)d_in[21];     w.bo = (const float*)d_in[22];
    w.wxo = (const float*)d_in[23];    w.bxo = (const float*)d_in[24];
    w.wgo = (const float*)d_in[25];    w.bgo = (const float*)d_in[26];

    int nb = (N + 255) / 256, eb = (E + 255) / 256;
    k_init_small<<<1, 256, 0, stream>>>(p, w);
    k_init_nodes<<<nb, 256, 0, stream>>>(p, w);
    k_hist<<<eb, 256, 0, stream>>>(p);
    k_scan<<<1, SCAN_T, 0, stream>>>(p);
    k_build<<<eb, 256, 0, stream>>>(p);
    for (int s = 0; s < 2; s++) {
        if (s == 0) k_edge<1, 1><<<eb, 256, 0, stream>>>(p, s);
        else        k_edge<0, 0><<<eb, 256, 0, stream>>>(p, s);
        k_node<<<nb, 256, 0, stream>>>(p, s);
        k_global<<<1, 256, 0, stream>>>(p, s);
    }
}

// Round 17
// 780.875 us; speedup vs baseline: 1.1339x; 1.1339x over previous
//
#include <hip/hip_runtime.h>

#define DEV __device__ __forceinline__

DEV float relu(float v) { return v > 0.f ? v : 0.f; }

// ---- small-region layout (float offsets) ----
#define G1_OFF 0
#define GIN_OFF 16
#define WEE 48
#define BEE 64
#define WC  80      // We_core [98][16]
#define BC  1648
#define WD  1664    // We_dec [16][16]
#define BD  1920
#define WO  1936    // We_out [16][2]
#define BO  1968
#define WXE 1972
#define BXE 1988
#define WXC 2004    // Wx_core [50][16]
#define BXC 2804
#define WXD 2820
#define BXD 3076
#define WXO 3092
#define BXO 3124
#define WGE 3126
#define BGE 3127
#define WGC 3128
#define BGC 3162
#define WGD 3163
#define BGD 3164
#define WGO 3165
#define BGO 3166
#define SMALL_N 3200

struct P {
    const float *x, *e, *g;
    const int *src, *dst, *nidx, *eidx;
    float *ec, *xin, *agg, *small, *eagg_rep, *nagg_rep;  // ec CSR-ordered
    int *cnt, *rowptr, *cursor, *origidx;
    float *eperm;        // e values in CSR order
    int *spk;            // src | (eidx<<24) in CSR order
    int *dstperm;        // dst in CSR order (sorted)
    float *out;
    int N, E, B;
};

struct WIn {
    const float *we_enc, *be_enc, *wx_enc, *bx_enc, *wg_enc, *bg_enc;
    const float *wc, *bc, *wxc, *bxc, *wgc, *bgc;
    const float *wd, *bd, *wxd, *bxd, *wgd, *bgd;
    const float *wo, *bo, *wxo, *bxo, *wgo, *bgo;
};

__global__ __launch_bounds__(256) void k_init_small(P p, WIn w) {
    int t = threadIdx.x;
    float* S = p.small;
#define CP(ptr, off, len) for (int i = t; i < (len); i += 256) S[(off) + i] = ptr[i];
    CP(w.we_enc, WEE, 16) CP(w.be_enc, BEE, 16)
    CP(w.wc, WC, 1568)    CP(w.bc, BC, 16)
    CP(w.wd, WD, 256)     CP(w.bd, BD, 16)
    CP(w.wo, WO, 32)      CP(w.bo, BO, 2)
    CP(w.wx_enc, WXE, 16) CP(w.bx_enc, BXE, 16)
    CP(w.wxc, WXC, 800)   CP(w.bxc, BXC, 16)
    CP(w.wxd, WXD, 256)   CP(w.bxd, BXD, 16)
    CP(w.wxo, WXO, 32)    CP(w.bxo, BXO, 2)
    CP(w.wgc, WGC, 34)
#undef CP
    if (t == 0) {
        S[WGE] = w.wg_enc[0]; S[BGE] = w.bg_enc[0];
        S[BGC] = w.bgc[0];
        S[WGD] = w.wgd[0];    S[BGD] = w.bgd[0];
        S[WGO] = w.wgo[0];    S[BGO] = w.bgo[0];
    }
    if (t < p.B) {
        float gv = p.g[t];
        float g1 = relu(gv * w.wg_enc[0] + w.bg_enc[0]);
        S[G1_OFF + t] = g1;
        S[GIN_OFF + 2 * t] = g1;
        S[GIN_OFF + 2 * t + 1] = g1;   // gc starts as g1
    }
    for (int r = t; r < 16 * 256; r += 256) p.nagg_rep[r] = 0.f;
    for (int r = t; r < 64 * 256; r += 256) p.eagg_rep[r] = 0.f;
}

__global__ __launch_bounds__(256) void k_init_nodes(P p, WIn w) {
    size_t n = (size_t)blockIdx.x * 256 + threadIdx.x;
    if (n >= (size_t)p.N) return;
    p.cnt[n] = 0;
    float xv = p.x[n];
    float* row = p.xin + n * 32;
#pragma unroll
    for (int h = 0; h < 16; h++) {
        float v = relu(xv * w.wx_enc[h] + w.bx_enc[h]);
        row[h] = v;
        row[16 + h] = v;   // xc starts as x1
    }
    float4 z = make_float4(0.f, 0.f, 0.f, 0.f);
    float4* a = (float4*)(p.agg + n * 16);
#pragma unroll
    for (int c = 0; c < 4; c++) a[c] = z;   // boundary-run atomics need zeroed base
}

__global__ __launch_bounds__(256) void k_hist(P p) {
    size_t i = (size_t)blockIdx.x * 256 + threadIdx.x;
    if (i >= (size_t)p.E) return;
    atomicAdd(&p.cnt[p.dst[i]], 1);
}

// single-block exclusive scan of cnt[0..N) -> rowptr[0..N] and cursor copy
#define SCAN_T 1024
#define SCAN_V 4
__global__ __launch_bounds__(SCAN_T) void k_scan(P p) {
    __shared__ int wsum[16];
    __shared__ int carry_s;
    int t = threadIdx.x;
    int lane = t & 63, wid = t >> 6;
    if (t == 0) carry_s = 0;
    __syncthreads();
    int chunk = SCAN_T * SCAN_V;
    int nchunk = (p.N + chunk - 1) / chunk;
    for (int c = 0; c < nchunk; c++) {
        int base = c * chunk + t * SCAN_V;
        int v[SCAN_V];
        int s = 0;
#pragma unroll
        for (int k = 0; k < SCAN_V; k++) {
            int idx = base + k;
            v[k] = (idx < p.N) ? p.cnt[idx] : 0;
            s += v[k];
        }
        int incl = s;
#pragma unroll
        for (int off = 1; off < 64; off <<= 1) {
            int u = __shfl_up(incl, off);
            if (lane >= off) incl += u;
        }
        if (lane == 63) wsum[wid] = incl;
        __syncthreads();
        if (wid == 0) {
            int ws = (lane < 16) ? wsum[lane] : 0;
            int wincl = ws;
#pragma unroll
            for (int off = 1; off < 16; off <<= 1) {
                int u = __shfl_up(wincl, off);
                if (lane >= off) wincl += u;
            }
            if (lane < 16) wsum[lane] = wincl - ws;
        }
        __syncthreads();
        int carry = carry_s;
        int excl = carry + wsum[wid] + incl - s;
        int run = excl;
#pragma unroll
        for (int k = 0; k < SCAN_V; k++) {
            int idx = base + k;
            if (idx < p.N) { p.rowptr[idx] = run; p.cursor[idx] = run; }
            run += v[k];
        }
        __syncthreads();
        if (t == SCAN_T - 1) carry_s = excl + s;
        __syncthreads();
    }
    if (t == 0) p.rowptr[p.N] = carry_s;
}

// merged scatter+permute: place each edge directly into its CSR slot
__global__ __launch_bounds__(256) void k_build(P p) {
    size_t i = (size_t)blockIdx.x * 256 + threadIdx.x;
    if (i >= (size_t)p.E) return;
    int d = p.dst[i];
    int slot = atomicAdd(&p.cursor[d], 1);
    p.eperm[slot] = p.e[i];
    p.spk[slot] = p.src[i] | (p.eidx[i] << 24);
    p.dstperm[slot] = d;
    p.origidx[slot] = (int)i;
}

template <int STEP0, int SAVE_EC>
__global__ __launch_bounds__(256) void k_edge(P p, int s) {
    __shared__ float eagg_lds[16 * 17];   // single replica (round-7 config: 31K conflicts)
    const int t = threadIdx.x;
    const int lane = t & 63;
    for (int r = t; r < 16 * 17; r += 256) eagg_lds[r] = 0.f;
    __syncthreads();
    const size_t j = (size_t)blockIdx.x * 256 + t;
    const float* __restrict__ S = p.small;
    float enew[16];
#pragma unroll
    for (int h = 0; h < 16; h++) enew[h] = 0.f;
    int di = -1;
    const bool valid = j < (size_t)p.E;
    if (valid) {
        float acc[16];
#pragma unroll
        for (int h = 0; h < 16; h++) acc[h] = S[BC + h];
        float ev = p.eperm[j];
        unsigned sp = (unsigned)p.spk[j];
        int si = (int)(sp & 0xFFFFFFu);
        int b = (int)(sp >> 24);
        di = p.dstperm[j];
        float e1v[16];
#pragma unroll
        for (int h = 0; h < 16; h++) e1v[h] = relu(ev * S[WEE + h] + S[BEE + h]);
#pragma unroll
        for (int jj = 0; jj < 16; jj++)
#pragma unroll
            for (int h = 0; h < 16; h++) acc[h] += e1v[jj] * S[WC + jj * 16 + h];
        if (STEP0) {
#pragma unroll
            for (int jj = 0; jj < 16; jj++)
#pragma unroll
                for (int h = 0; h < 16; h++) acc[h] += e1v[jj] * S[WC + (16 + jj) * 16 + h];
        } else {
            const float4* ecv = (const float4*)(p.ec + j * 16);
#pragma unroll
            for (int c = 0; c < 4; c++) {
                float4 v = ecv[c];
                float vv[4] = {v.x, v.y, v.z, v.w};
#pragma unroll
                for (int k = 0; k < 4; k++)
#pragma unroll
                    for (int h = 0; h < 16; h++) acc[h] += vv[k] * S[WC + (16 + c * 4 + k) * 16 + h];
            }
        }
        // x_in[src] random gather; x_in[dst] wave-local (dst sorted)
        const float4* xs = (const float4*)(p.xin + (size_t)si * 32);
#pragma unroll
        for (int c = 0; c < 8; c++) {
            float4 v = xs[c];
            float vv[4] = {v.x, v.y, v.z, v.w};
#pragma unroll
            for (int k = 0; k < 4; k++)
#pragma unroll
                for (int h = 0; h < 16; h++) acc[h] += vv[k] * S[WC + (32 + c * 4 + k) * 16 + h];
        }
        const float4* xd = (const float4*)(p.xin + (size_t)di * 32);
#pragma unroll
        for (int c = 0; c < 8; c++) {
            float4 v = xd[c];
            float vv[4] = {v.x, v.y, v.z, v.w};
#pragma unroll
            for (int k = 0; k < 4; k++)
#pragma unroll
                for (int h = 0; h < 16; h++) acc[h] += vv[k] * S[WC + (64 + c * 4 + k) * 16 + h];
        }
        float g0 = S[GIN_OFF + 2 * b], gcv = S[GIN_OFF + 2 * b + 1];
#pragma unroll
        for (int h = 0; h < 16; h++) acc[h] += g0 * S[WC + 96 * 16 + h] + gcv * S[WC + 97 * 16 + h];
#pragma unroll
        for (int h = 0; h < 16; h++) enew[h] = relu(acc[h]);
        if (SAVE_EC) {   // next step's k_edge input; dead on the last step
            float4* eco = (float4*)(p.ec + j * 16);
#pragma unroll
            for (int c = 0; c < 4; c++)
                eco[c] = make_float4(enew[c * 4], enew[c * 4 + 1], enew[c * 4 + 2], enew[c * 4 + 3]);
        }
        // per-graph edge aggregate
#pragma unroll
        for (int h = 0; h < 16; h++) atomicAdd(&eagg_lds[b * 17 + h], enew[h]);
        // fused decoder + output (scattered 8B store at original edge index)
        int i = p.origidx[j];
        float d[16];
#pragma unroll
        for (int h2 = 0; h2 < 16; h2++) d[h2] = S[BD + h2];
#pragma unroll
        for (int h = 0; h < 16; h++)
#pragma unroll
            for (int h2 = 0; h2 < 16; h2++) d[h2] += enew[h] * S[WD + h * 16 + h2];
        float o0 = S[BO], o1 = S[BO + 1];
#pragma unroll
        for (int h2 = 0; h2 < 16; h2++) {
            float dv = relu(d[h2]);
            o0 += dv * S[WO + h2 * 2];
            o1 += dv * S[WO + h2 * 2 + 1];
        }
        ((float2*)p.out)[(size_t)s * p.E + i] = make_float2(o0, o1);
    }
    // wave-level segmented inclusive scan over dst runs (dst sorted; no LDS, no barrier)
    float ssum[16];
#pragma unroll
    for (int h = 0; h < 16; h++) ssum[h] = enew[h];
    int cnt = valid ? 1 : 0;
#pragma unroll
    for (int o = 0; o < 6; o++) {
        int off = 1 << o;
        int du = __shfl_up(di, off);
        int cu = __shfl_up(cnt, off);
        bool pred = (lane >= off) && (du == di);
        if (pred) cnt += cu;
#pragma unroll
        for (int h = 0; h < 16; h++) {
            float su = __shfl_up(ssum[h], off);
            if (pred) ssum[h] += su;
        }
    }
    int dn = __shfl_down(di, 1);
    if (valid && (lane == 63 || dn != di)) {   // run-end lane (within wave)
        size_t jstart = j - (size_t)cnt + 1;
        int rs = p.rowptr[di], re = p.rowptr[di + 1];
        float* arow = p.agg + (size_t)di * 16;
        if (jstart == (size_t)rs && j + 1 == (size_t)re) {
            // full row contained in this wave: plain store
#pragma unroll
            for (int h = 0; h < 16; h++) arow[h] = ssum[h];
        } else {
            // row split across waves/blocks: atomic onto zeroed base
#pragma unroll
            for (int h = 0; h < 16; h++) atomicAdd(arow + h, ssum[h]);
        }
    }
    __syncthreads();
    // flush block-local edge_agg to replicated global accumulators
    {
        float v = eagg_lds[(t >> 4) * 17 + (t & 15)];
        if (v != 0.f)
            atomicAdd(p.eagg_rep + (size_t)(blockIdx.x & 63) * 256 + t, v);
    }
}

__global__ __launch_bounds__(256) void k_node(P p, int s) {
    const size_t n = (size_t)blockIdx.x * 256 + threadIdx.x;
    const bool valid = n < (size_t)p.N;
    const float* __restrict__ S = p.small;
    float xnew[16];
    int b = 0;
    if (valid) {
        float acc[16];
#pragma unroll
        for (int h = 0; h < 16; h++) acc[h] = S[BXC + h];
        float xv = p.x[n];
        float x1v[16];
#pragma unroll
        for (int h = 0; h < 16; h++) x1v[h] = relu(xv * S[WXE + h] + S[BXE + h]);
#pragma unroll
        for (int jj = 0; jj < 16; jj++)
#pragma unroll
            for (int h = 0; h < 16; h++) acc[h] += x1v[jj] * S[WXC + jj * 16 + h];
        const float4* xcv = (const float4*)(p.xin + n * 32 + 16);
#pragma unroll
        for (int c = 0; c < 4; c++) {
            float4 v = xcv[c];
            float vv[4] = {v.x, v.y, v.z, v.w};
#pragma unroll
            for (int k = 0; k < 4; k++)
#pragma unroll
                for (int h = 0; h < 16; h++) acc[h] += vv[k] * S[WXC + (16 + c * 4 + k) * 16 + h];
        }
        // agg_e precomputed by k_edge (rows 32-47); zero for next step after use
        int cnt = p.rowptr[n + 1] - p.rowptr[n];
        float inv = (cnt > 0) ? 1.f / (float)cnt : 1.f;
        float4* arow = (float4*)(p.agg + n * 16);
#pragma unroll
        for (int c = 0; c < 4; c++) {
            float4 v = arow[c];
            float vv[4] = {v.x, v.y, v.z, v.w};
#pragma unroll
            for (int k = 0; k < 4; k++) {
                float av = vv[k] * inv;
#pragma unroll
                for (int h = 0; h < 16; h++) acc[h] += av * S[WXC + (32 + c * 4 + k) * 16 + h];
            }
            arow[c] = make_float4(0.f, 0.f, 0.f, 0.f);
        }
        b = p.nidx[n];
        float g0 = S[GIN_OFF + 2 * b], gcv = S[GIN_OFF + 2 * b + 1];
#pragma unroll
        for (int h = 0; h < 16; h++) acc[h] += g0 * S[WXC + 48 * 16 + h] + gcv * S[WXC + 49 * 16 + h];
#pragma unroll
        for (int h = 0; h < 16; h++) xnew[h] = relu(acc[h]);
        float4* xo = (float4*)(p.xin + n * 32 + 16);
#pragma unroll
        for (int c = 0; c < 4; c++)
            xo[c] = make_float4(xnew[c * 4], xnew[c * 4 + 1], xnew[c * 4 + 2], xnew[c * 4 + 3]);
        float d[16];
#pragma unroll
        for (int h2 = 0; h2 < 16; h2++) d[h2] = S[BXD + h2];
#pragma unroll
        for (int h = 0; h < 16; h++)
#pragma unroll
            for (int h2 = 0; h2 < 16; h2++) d[h2] += xnew[h] * S[WXD + h * 16 + h2];
        float o0 = S[BXO], o1 = S[BXO + 1];
#pragma unroll
        for (int h2 = 0; h2 < 16; h2++) {
            float dv = relu(d[h2]);
            o0 += dv * S[WXO + h2 * 2];
            o1 += dv * S[WXO + h2 * 2 + 1];
        }
        ((float2*)p.out)[(size_t)2 * p.E + (size_t)s * p.N + n] = make_float2(o0, o1);
    } else {
#pragma unroll
        for (int h = 0; h < 16; h++) xnew[h] = 0.f;
    }
    // node_agg: per-wave reduce (node_idx sorted -> wave-uniform almost always)
    int b0 = __shfl(b, 0);
    bool uni = __all(!valid || b == b0);
    float* rep = p.nagg_rep + (size_t)(blockIdx.x & 15) * 256;
    if (uni) {
#pragma unroll
        for (int h = 0; h < 16; h++) {
            float v = xnew[h];
            v += __shfl_down(v, 32); v += __shfl_down(v, 16); v += __shfl_down(v, 8);
            v += __shfl_down(v, 4);  v += __shfl_down(v, 2);  v += __shfl_down(v, 1);
            if ((threadIdx.x & 63) == 0) atomicAdd(rep + b0 * 16 + h, v);
        }
    } else if (valid) {
#pragma unroll
        for (int h = 0; h < 16; h++) atomicAdd(rep + b * 16 + h, xnew[h]);
    }
}

__global__ __launch_bounds__(256) void k_global(P p, int s) {
    __shared__ float na[256], ea[256];
    int t = threadIdx.x;
    float sn = 0.f, se = 0.f;
    for (int r = 0; r < 16; r++) sn += p.nagg_rep[r * 256 + t];
    for (int r = 0; r < 64; r++) se += p.eagg_rep[r * 256 + t];
    na[t] = sn;
    ea[t] = se;
    __syncthreads();
    if (t < p.B) {
        const float* S = p.small;
        float g0 = S[GIN_OFF + 2 * t], gcv = S[GIN_OFF + 2 * t + 1];
        float acc = S[BGC] + g0 * S[WGC + 0] + gcv * S[WGC + 1];
#pragma unroll
        for (int h = 0; h < 16; h++) acc += na[t * 16 + h] * S[WGC + 2 + h];
#pragma unroll
        for (int h = 0; h < 16; h++) acc += ea[t * 16 + h] * S[WGC + 18 + h];
        float gn = relu(acc);
        p.small[GIN_OFF + 2 * t + 1] = gn;
        float gd = relu(gn * S[WGD] + S[BGD]);
        float og = gd * S[WGO] + S[BGO];
        p.out[(size_t)4 * p.E + (size_t)4 * p.N + (size_t)s * p.B + t] = og;
    }
    __syncthreads();
    for (int r = t; r < 16 * 256; r += 256) p.nagg_rep[r] = 0.f;
    for (int r = t; r < 64 * 256; r += 256) p.eagg_rep[r] = 0.f;
}

extern "C" void kernel_launch(void* const* d_in, const int* in_sizes, int n_in,
                              void* d_out, int out_size, void* d_ws, size_t ws_size,
                              hipStream_t stream) {
    int N = in_sizes[0], E = in_sizes[1], B = in_sizes[2];
    P p;
    p.x = (const float*)d_in[0];
    p.e = (const float*)d_in[1];
    p.g = (const float*)d_in[2];
    const int* edges = (const int*)d_in[27];
    p.src = edges;
    p.dst = edges + E;
    p.nidx = (const int*)d_in[28];
    p.eidx = (const int*)d_in[29];

    float* ws = (float*)d_ws;
    size_t off = 0;
    p.ec = ws + off;        off += (size_t)E * 16;
    p.xin = ws + off;       off += (size_t)N * 32;
    p.agg = ws + off;       off += (size_t)N * 16;
    p.eagg_rep = ws + off;  off += 64 * 256;
    p.nagg_rep = ws + off;  off += 16 * 256;
    p.small = ws + off;     off += SMALL_N;
    p.cnt = (int*)(ws + off);     off += N;
    p.rowptr = (int*)(ws + off);  off += (size_t)N + 1;
    p.cursor = (int*)(ws + off);  off += N;
    p.origidx = (int*)(ws + off); off += E;
    p.eperm = ws + off;           off += E;
    p.spk = (int*)(ws + off);     off += E;
    p.dstperm = (int*)(ws + off); off += E;
    p.out = (float*)d_out;
    p.N = N; p.E = E; p.B = B;

    WIn w;
    w.we_enc = (const float*)d_in[3];  w.be_enc = (const float*)d_in[4];
    w.wx_enc = (const float*)d_in[5];  w.bx_enc = (const float*)d_in[6];
    w.wg_enc = (const float*)d_in[7];  w.bg_enc = (const float*)d_in[8];
    w.wc = (const float*)d_in[9];      w.bc = (const float*)d_in[10];
    w.wxc = (const float*)d_in[11];    w.bxc = (const float*)d_in[12];
    w.wgc = (const float*)d_in[13];    w.bgc = (const float*)d_in[14];
    w.wd = (const float*)d_in[15];     w.bd = (const float*)d_in[16];
    w.wxd = (const float*)d_in[17];    w.bxd = (const float*)d_in[18];
    w.wgd = (const float*)d_in[19];    w.bgd = (const float*)d_in[20];
    w.wo = (const float*)d_in[21];     w.bo = (const float*)d_in[22];
    w.wxo = (const float*)d_in[23];    w.bxo = (const float*)d_in[24];
    w.wgo = (const float*)d_in[25];    w.bgo = (const float*)d_in[26];

    int nb = (N + 255) / 256, eb = (E + 255) / 256;
    k_init_small<<<1, 256, 0, stream>>>(p, w);
    k_init_nodes<<<nb, 256, 0, stream>>>(p, w);
    k_hist<<<eb, 256, 0, stream>>>(p);
    k_scan<<<1, SCAN_T, 0, stream>>>(p);
    k_build<<<eb, 256, 0, stream>>>(p);
    for (int s = 0; s < 2; s++) {
        if (s == 0) k_edge<1, 1><<<eb, 256, 0, stream>>>(p, s);
        else        k_edge<0, 0><<<eb, 256, 0, stream>>>(p, s);
        k_node<<<nb, 256, 0, stream>>>(p, s);
        k_global<<<1, 256, 0, stream>>>(p, s);
    }
}